// Round 2
// baseline (601.849 us; speedup 1.0000x reference)
//
#include <hip/hip_runtime.h>

#define BB 4
#define S 128
#define SS (S*S)
#define BSS (BB*SS)
#define JSPLIT 8
#define ISPLIT 4

__device__ __forceinline__ int off3(int b, int i, int j) { return (b * S + i) * S + j; }
__device__ __forceinline__ int off4(int b, int i, int j, int k) { return ((b * S + i) * S + j) * S + k; }

// ---------------------------------------------------------------------------
// q = sigmoid(src), plus transposed copies. On init also copies src -> base.
// ws layout (floats): qb[0], qe[1], qs[2], qbT[3], qeT[4], qsT[5] each BSS.
// ---------------------------------------------------------------------------
__global__ __launch_bounds__(128) void k_sigmoid(const float* __restrict__ sb,
                                                 const float* __restrict__ se,
                                                 const float* __restrict__ ss,
                                                 float* base,
                                                 float* __restrict__ ws, int init) {
    int bi = blockIdx.x;
    int b = bi >> 7, i = bi & (S - 1);
    int j = threadIdx.x;
    const float* src[3] = {sb, se, ss};
#pragma unroll
    for (int t = 0; t < 3; ++t) {
        float x = src[t][off3(b, i, j)];
        float q = 1.0f / (1.0f + expf(-x));
        ws[t * BSS + off3(b, i, j)] = q;
        ws[(3 + t) * BSS + off3(b, j, i)] = q;
        if (init) base[t * BSS + off3(b, i, j)] = x;
    }
}

// ---------------------------------------------------------------------------
// 7 natural-layout tensors. wg = (jchunk, I, b). Half-wave (32 lanes) per j,
// each lane covers 4 k's via float4. Unique (b,I,j) owner -> plain RMW.
// ---------------------------------------------------------------------------
__global__ __launch_bounds__(256) void k_sib(
    const float* __restrict__ be, const float* __restrict__ bb,
    const float* __restrict__ cb, const float* __restrict__ eb,
    const float* __restrict__ ee, const float* __restrict__ ce,
    const float* __restrict__ sp, const int* __restrict__ edge,
    const int* __restrict__ chart, const float* __restrict__ ws,
    float* __restrict__ base) {
    const int b = blockIdx.z, I = blockIdx.y;
    const int jbase = blockIdx.x * (S / JSPLIT);
    const int t = threadIdx.x, w = t >> 6, l = t & 63;
    const int h = (l >> 5) & 1, lh = l & 31;
    const int k = 4 * lh;

    const float* qb = ws;
    const float* qe = ws + BSS;
    const float* qs = ws + 2 * BSS;
    const float* qbT = ws + 3 * BSS;
    const float* qeT = ws + 4 * BSS;

    const float4 qb_i = *(const float4*)&qb[off3(b, I, k)];
    const float4 qe_i = *(const float4*)&qe[off3(b, I, k)];
    const float4 qs_i = *(const float4*)&qs[off3(b, I, k)];
    const int4 ekv = *(const int4*)&edge[off3(b, I, k)];
    const int4 c0kv = *(const int4*)&chart[off3(b, 0, k)];
    const int Iprev = (I + S - 1) & (S - 1);
    bool ek[4], c0k[4];
#pragma unroll
    for (int c = 0; c < 4; ++c) {
        ek[c] = (&ekv.x)[c] != 0;
        c0k[c] = (&c0kv.x)[c] != 0;
    }

#pragma unroll
    for (int it = 0; it < (S / JSPLIT) / 8; ++it) {
        const int j = jbase + 8 * it + 2 * w + h;
        // prefetch old base values (uniform per half-wave -> broadcast)
        const float ob_b = base[0 * BSS + off3(b, I, j)];
        const float ob_e = base[1 * BSS + off3(b, I, j)];
        const float ob_s = base[2 * BSS + off3(b, I, j)];
        const bool e_ij = edge[off3(b, I, j)] != 0;
        const bool chIj = chart[off3(b, Iprev, j)] != 0;
        const bool c0j = chart[off3(b, 0, j)] != 0;
        const float4 qbT_j = *(const float4*)&qbT[off3(b, j, k)];
        const float4 qeT_j = *(const float4*)&qeT[off3(b, j, k)];

        const int b4 = off4(b, I, j, k);
        const float4 v_be = *(const float4*)&be[b4];
        const float4 v_bb = *(const float4*)&bb[b4];
        const float4 v_cb = *(const float4*)&cb[b4];
        const float4 v_eb = *(const float4*)&eb[b4];
        const float4 v_ee = *(const float4*)&ee[b4];
        const float4 v_ce = *(const float4*)&ce[b4];
        const float4 v_sp = *(const float4*)&sp[b4];

        const int mx = I > j ? I : j;
        const bool wmj = e_ij && (I != j);

        float accB = 0.f, accE = 0.f, accS = 0.f;
#pragma unroll
        for (int c = 0; c < 4; ++c) {
            const int kc = k + c;
            const bool wm = e_ij && ek[c] && (I != kc);
            const bool m2 = wm && (j != kc);
            const bool wk = ek[c] && wmj;
            const bool spn = chIj && (mx != kc) && c0j && c0k[c];
            accB += (wm ? (&qe_i.x)[c] : 0.f) * (&v_be.x)[c] +
                    (m2 ? (&qb_i.x)[c] : 0.f) * (&v_bb.x)[c] +
                    (m2 ? (&qbT_j.x)[c] : 0.f) * (&v_cb.x)[c];
            accE += (wk ? (&qb_i.x)[c] : 0.f) * (&v_eb.x)[c] +
                    (m2 ? (&qe_i.x)[c] : 0.f) * (&v_ee.x)[c] +
                    (m2 ? (&qeT_j.x)[c] : 0.f) * (&v_ce.x)[c];
            accS += (spn ? (&qs_i.x)[c] : 0.f) * (&v_sp.x)[c];
        }

#pragma unroll
        for (int o = 16; o > 0; o >>= 1) {
            accB += __shfl_xor(accB, o);
            accE += __shfl_xor(accE, o);
            accS += __shfl_xor(accS, o);
        }
        if (lh == 0) {
            base[0 * BSS + off3(b, I, j)] = ob_b + accB;
            base[1 * BSS + off3(b, I, j)] = ob_e + accE;
            base[2 * BSS + off3(b, I, j)] = ob_s + accS;
        }
    }
}

// ---------------------------------------------------------------------------
// s_grd_b / s_grd_e single pass. wg = (isplit, J, b). Half-wave per I,
// lanes cover 4 K's via float4.
// ---------------------------------------------------------------------------
__global__ __launch_bounds__(256) void k_grd(
    const float* __restrict__ gb, const float* __restrict__ ge,
    const int* __restrict__ edge, const int* __restrict__ chart,
    const float* __restrict__ ws, float* __restrict__ base) {
    const int b = blockIdx.z, J = blockIdx.y, is = blockIdx.x;
    const int t = threadIdx.x, w = t >> 6, l = t & 63;
    const int h = (l >> 5) & 1, lh = l & 31;
    const int K = 4 * lh;

    const float* qs = ws + 2 * BSS;
    const float* qbT = ws + 3 * BSS;
    const float* qeT = ws + 4 * BSS;
    const float* qsT = ws + 5 * BSS;

    const float4 qs_J = *(const float4*)&qs[off3(b, J, K)];
    const float4 qsT_J = *(const float4*)&qsT[off3(b, J, K)];
    const int4 c0Kv = *(const int4*)&chart[off3(b, 0, K)];
    const bool c0J = chart[off3(b, 0, J)] != 0;
    const int Jprev = (J + S - 1) & (S - 1);
    const int4 chJKv = *(const int4*)&chart[off3(b, Jprev, K)];
    bool c0K[4], chJK[4], chKJ[4];
    int mxJ[4];
#pragma unroll
    for (int c = 0; c < 4; ++c) {
        c0K[c] = (&c0Kv.x)[c] != 0;
        chJK[c] = (&chJKv.x)[c] != 0;
        chKJ[c] = chart[off3(b, (K + c + S - 1) & (S - 1), J)] != 0;
        mxJ[c] = J > (K + c) ? J : (K + c);
    }

    float rsb[4] = {0.f, 0.f, 0.f, 0.f}, rse[4] = {0.f, 0.f, 0.f, 0.f};

#pragma unroll
    for (int itI = 0; itI < (S / ISPLIT) / 8; ++itI) {
        const int I = is * (S / ISPLIT) + 8 * itI + 2 * w + h;
        const float ob0 = base[0 * BSS + off3(b, I, J)];
        const float ob1 = base[1 * BSS + off3(b, I, J)];
        const float4 v_b = *(const float4*)&gb[off4(b, I, J, K)];
        const float4 v_e = *(const float4*)&ge[off4(b, I, J, K)];
        const int4 eIKv = *(const int4*)&edge[off3(b, I, K)];
        const bool eIJ = edge[off3(b, I, J)] != 0;
        const bool c0I = chart[off3(b, 0, I)] != 0;
        const float qbT_JI = qbT[off3(b, J, I)];
        const float qeT_JI = qeT[off3(b, J, I)];

        float pb = 0.f, pe = 0.f;
#pragma unroll
        for (int c = 0; c < 4; ++c) {
            const int Kc = K + c;
            const bool eIK = (&eIKv.x)[c] != 0;
            const float vb = (&v_b.x)[c], ve = (&v_e.x)[c];
            const bool nc1 = eIJ && eIK && (I != Kc) && (J <= Kc) && (J >= I || Kc <= I);
            const bool nc2 = eIK && eIJ && (I != J) && (Kc <= J) && (Kc >= I || J <= I);
            pb += (nc1 ? (&qs_J.x)[c] : 0.f) * vb;
            pe += (nc2 ? (&qsT_J.x)[c] : 0.f) * ve;
            const bool o1 = !((J <= I) && (Kc >= I)) && chJK[c] && (mxJ[c] != I) && c0K[c] && c0I;
            const bool o2 = !((Kc <= I) && (J >= I)) && chKJ[c] && (mxJ[c] != I) && c0J && c0I;
            rsb[c] += (o1 ? qbT_JI : 0.f) * vb;
            rse[c] += (o2 ? qeT_JI : 0.f) * ve;
        }

#pragma unroll
        for (int o = 16; o > 0; o >>= 1) {
            pb += __shfl_xor(pb, o);
            pe += __shfl_xor(pe, o);
        }
        if (lh == 0) {
            base[0 * BSS + off3(b, I, J)] = ob0 + pb;
            base[1 * BSS + off3(b, I, J)] = ob1 + pe;
        }
    }

    // combine the two halves' span accumulators, then atomically commit
#pragma unroll
    for (int c = 0; c < 4; ++c) {
        rsb[c] += __shfl_xor(rsb[c], 32);
        rse[c] += __shfl_xor(rse[c], 32);
    }
    if (h == 0) {
#pragma unroll
        for (int c = 0; c < 4; ++c) {
            atomicAdd(&base[2 * BSS + off3(b, J, K + c)], rsb[c]);
            atomicAdd(&base[2 * BSS + off3(b, K + c, J)], rse[c]);
        }
    }
}

extern "C" void kernel_launch(void* const* d_in, const int* in_sizes, int n_in,
                              void* d_out, int out_size, void* d_ws, size_t ws_size,
                              hipStream_t stream) {
    (void)in_sizes; (void)n_in; (void)out_size; (void)ws_size;
    const float* s_const = (const float*)d_in[0];
    const float* s_arg_begin = (const float*)d_in[1];
    const float* s_arg_end = (const float*)d_in[2];
    const float* be = (const float*)d_in[3];
    const float* eb = (const float*)d_in[4];
    const float* bb = (const float*)d_in[5];
    const float* ee = (const float*)d_in[6];
    const float* cb = (const float*)d_in[7];
    const float* ce = (const float*)d_in[8];
    const float* gb = (const float*)d_in[9];
    const float* ge = (const float*)d_in[10];
    const float* sp = (const float*)d_in[11];
    const int* edge = (const int*)d_in[12];
    const int* chart = (const int*)d_in[13];
    float* base = (float*)d_out;
    float* ws = (float*)d_ws;

    for (int it = 0; it < 3; ++it) {
        if (it == 0)
            k_sigmoid<<<dim3(BB * S), dim3(S), 0, stream>>>(s_arg_begin, s_arg_end, s_const,
                                                            base, ws, 1);
        else
            k_sigmoid<<<dim3(BB * S), dim3(S), 0, stream>>>(base, base + BSS, base + 2 * BSS,
                                                            base, ws, 0);
        k_sib<<<dim3(JSPLIT, S, BB), dim3(256), 0, stream>>>(be, bb, cb, eb, ee, ce, sp,
                                                             edge, chart, ws, base);
        k_grd<<<dim3(ISPLIT, S, BB), dim3(256), 0, stream>>>(gb, ge, edge, chart, ws, base);
    }
}

// Round 3
// 534.759 us; speedup vs baseline: 1.1255x; 1.1255x over previous
//
#include <hip/hip_runtime.h>

#define BB 4
#define S 128
#define SS (S*S)
#define BSS (BB*SS)

__device__ __forceinline__ int off3(int b, int i, int j) { return (b * S + i) * S + j; }
__device__ __forceinline__ int off4(int b, int i, int j, int k) { return ((b * S + i) * S + j) * S + k; }

// ---------------------------------------------------------------------------
// q = sigmoid(src) + transposed copies. init: also base <- src.
// ws: qb[0], qe[1], qs[2], qbT[3], qeT[4], qsT[5], each BSS floats.
// ---------------------------------------------------------------------------
__global__ __launch_bounds__(128) void k_sigmoid(const float* __restrict__ sb,
                                                 const float* __restrict__ se,
                                                 const float* __restrict__ ss,
                                                 float* base,
                                                 float* __restrict__ ws, int init) {
    int bi = blockIdx.x;
    int b = bi >> 7, i = bi & (S - 1);
    int j = threadIdx.x;
    const float* src[3] = {sb, se, ss};
#pragma unroll
    for (int t = 0; t < 3; ++t) {
        float x = src[t][off3(b, i, j)];
        float q = 1.0f / (1.0f + expf(-x));
        ws[t * BSS + off3(b, i, j)] = q;
        ws[(3 + t) * BSS + off3(b, j, i)] = q;
        if (init) base[t * BSS + off3(b, i, j)] = x;
    }
}

// ---------------------------------------------------------------------------
// One einsum term per block; each block streams ONE contiguous-ish 64KB slab
// of ONE tensor (breaks the 9-way power-of-2 multi-stream DRAM aliasing).
// grid = (128, 9, B). y<7: row terms, block (b, I=x) streams A[b,I,:,:].
// y in {7,8}: gb/ge fused edge+span, block (b, Jtile=x&15, Isplit=x>>4)
// streams A[b, I0:I0+16, 8Jt:8Jt+8, :] (4KB contiguous per I-step).
// 256 thr = 8 half-waves; half-wave owns one j (or J); lane covers 4 k's.
// All output commits are atomicAdd onto base (init'd by k_sigmoid).
// ---------------------------------------------------------------------------
__global__ __launch_bounds__(256) void k_terms(
    const float* __restrict__ be, const float* __restrict__ bb,
    const float* __restrict__ cb, const float* __restrict__ eb,
    const float* __restrict__ ee, const float* __restrict__ ce,
    const float* __restrict__ sp, const float* __restrict__ gb,
    const float* __restrict__ ge, const int* __restrict__ edge,
    const int* __restrict__ chart, const float* __restrict__ ws,
    float* __restrict__ base) {
    const int b = blockIdx.z, y = blockIdx.y, x = blockIdx.x;
    const int t = threadIdx.x, hw = t >> 5, lh = t & 31;
    const int K = 4 * lh;

    const float* qb = ws;
    const float* qe = ws + BSS;
    const float* qs = ws + 2 * BSS;
    const float* qbT = ws + 3 * BSS;
    const float* qeT = ws + 4 * BSS;
    const float* qsT = ws + 5 * BSS;

    if (y < 7) {
        const int I = x;
        const float* A;
        int plane;
        switch (y) {
            case 0: A = be; plane = 0; break;
            case 1: A = bb; plane = 0; break;
            case 2: A = cb; plane = 0; break;
            case 3: A = eb; plane = 1; break;
            case 4: A = ee; plane = 1; break;
            case 5: A = ce; plane = 1; break;
            default: A = sp; plane = 2; break;
        }
        // block-constant coefficient row (for y!=2,5)
        const float* qrow = (y == 0 || y == 4) ? qe : (y == 1 || y == 3) ? qb : qs;
        const float4 coefI = *(const float4*)&qrow[off3(b, I, K)];
        const int4 ekv = *(const int4*)&edge[off3(b, I, K)];
        const int4 c0kv = *(const int4*)&chart[off3(b, 0, K)];
        const int Iprev = (I + S - 1) & (S - 1);
        bool ek[4], c0k[4];
#pragma unroll
        for (int c = 0; c < 4; ++c) {
            ek[c] = (&ekv.x)[c] != 0;
            c0k[c] = (&c0kv.x)[c] != 0;
        }

#pragma unroll
        for (int jj = 0; jj < 16; ++jj) {
            const int j = 8 * jj + hw;
            const float4 v = *(const float4*)&A[off4(b, I, j, K)];
            float4 coef = coefI;
            if (y == 2) coef = *(const float4*)&qbT[off3(b, j, K)];
            if (y == 5) coef = *(const float4*)&qeT[off3(b, j, K)];
            const bool e_ij = edge[off3(b, I, j)] != 0;
            const bool chIj = chart[off3(b, Iprev, j)] != 0;
            const bool c0j = chart[off3(b, 0, j)] != 0;
            const int mx = I > j ? I : j;
            const bool wkj = e_ij && (I != j);  // for y==3

            float acc = 0.f;
#pragma unroll
            for (int c = 0; c < 4; ++c) {
                const int kc = K + c;
                bool m;
                if (y == 0) {
                    m = e_ij && ek[c] && (I != kc);
                } else if (y == 3) {
                    m = ek[c] && wkj;
                } else if (y == 6) {
                    m = chIj && (mx != kc) && c0j && c0k[c];
                } else {  // y in {1,2,4,5}: full mask2o
                    m = e_ij && ek[c] && (I != kc) && (j != kc);
                }
                acc += (m ? (&coef.x)[c] : 0.f) * (&v.x)[c];
            }
#pragma unroll
            for (int o = 16; o > 0; o >>= 1) acc += __shfl_xor(acc, o);
            if (lh == 0) atomicAdd(&base[plane * BSS + off3(b, I, j)], acc);
        }
    } else {
        // y==7: gb (edge->plane0, span->plane2[J,K]); y==8: ge (edge->plane1, span->plane2[K,J])
        const float* A = (y == 7) ? gb : ge;
        const float* qT = (y == 7) ? qbT : qeT;
        const int Jt = x & 15, Is = x >> 4;
        const int J = 8 * Jt + hw, I0 = 16 * Is;

        const float4 q_J = (y == 7) ? *(const float4*)&qs[off3(b, J, K)]
                                    : *(const float4*)&qsT[off3(b, J, K)];
        const int4 c0Kv = *(const int4*)&chart[off3(b, 0, K)];
        const bool c0J = chart[off3(b, 0, J)] != 0;
        const int Jprev = (J + S - 1) & (S - 1);
        const int4 chJKv = *(const int4*)&chart[off3(b, Jprev, K)];
        bool c0K[4], chJK[4], chKJ[4];
        int mxJ[4];
#pragma unroll
        for (int c = 0; c < 4; ++c) {
            c0K[c] = (&c0Kv.x)[c] != 0;
            chJK[c] = (&chJKv.x)[c] != 0;
            chKJ[c] = (y == 8) ? (chart[off3(b, (K + c + S - 1) & (S - 1), J)] != 0) : false;
            mxJ[c] = J > (K + c) ? J : (K + c);
        }

        float rs[4] = {0.f, 0.f, 0.f, 0.f};

#pragma unroll
        for (int s = 0; s < 16; ++s) {
            const int I = I0 + s;
            const float4 v = *(const float4*)&A[off4(b, I, J, K)];
            const int4 eIKv = *(const int4*)&edge[off3(b, I, K)];
            const bool eIJ = edge[off3(b, I, J)] != 0;
            const bool c0I = chart[off3(b, 0, I)] != 0;
            const float qT_JI = qT[off3(b, J, I)];

            float p = 0.f;
#pragma unroll
            for (int c = 0; c < 4; ++c) {
                const int Kc = K + c;
                const bool eIK = (&eIKv.x)[c] != 0;
                const float vv = (&v.x)[c];
                bool nc, o;
                if (y == 7) {
                    nc = eIJ && eIK && (I != Kc) && (J <= Kc) && (J >= I || Kc <= I);
                    o = !((J <= I) && (Kc >= I)) && chJK[c] && (mxJ[c] != I) && c0K[c] && c0I;
                } else {
                    nc = eIK && eIJ && (I != J) && (Kc <= J) && (Kc >= I || J <= I);
                    o = !((Kc <= I) && (J >= I)) && chKJ[c] && (mxJ[c] != I) && c0J && c0I;
                }
                p += (nc ? (&q_J.x)[c] : 0.f) * vv;
                rs[c] += (o ? qT_JI : 0.f) * vv;
            }
#pragma unroll
            for (int o = 16; o > 0; o >>= 1) p += __shfl_xor(p, o);
            if (lh == 0) atomicAdd(&base[(y == 7 ? 0 : 1) * BSS + off3(b, I, J)], p);
        }

#pragma unroll
        for (int c = 0; c < 4; ++c) {
            if (y == 7)
                atomicAdd(&base[2 * BSS + off3(b, J, K + c)], rs[c]);
            else
                atomicAdd(&base[2 * BSS + off3(b, K + c, J)], rs[c]);
        }
    }
}

extern "C" void kernel_launch(void* const* d_in, const int* in_sizes, int n_in,
                              void* d_out, int out_size, void* d_ws, size_t ws_size,
                              hipStream_t stream) {
    (void)in_sizes; (void)n_in; (void)out_size; (void)ws_size;
    const float* s_const = (const float*)d_in[0];
    const float* s_arg_begin = (const float*)d_in[1];
    const float* s_arg_end = (const float*)d_in[2];
    const float* be = (const float*)d_in[3];
    const float* eb = (const float*)d_in[4];
    const float* bb = (const float*)d_in[5];
    const float* ee = (const float*)d_in[6];
    const float* cb = (const float*)d_in[7];
    const float* ce = (const float*)d_in[8];
    const float* gb = (const float*)d_in[9];
    const float* ge = (const float*)d_in[10];
    const float* sp = (const float*)d_in[11];
    const int* edge = (const int*)d_in[12];
    const int* chart = (const int*)d_in[13];
    float* base = (float*)d_out;
    float* ws = (float*)d_ws;

    for (int it = 0; it < 3; ++it) {
        if (it == 0)
            k_sigmoid<<<dim3(BB * S), dim3(S), 0, stream>>>(s_arg_begin, s_arg_end, s_const,
                                                            base, ws, 1);
        else
            k_sigmoid<<<dim3(BB * S), dim3(S), 0, stream>>>(base, base + BSS, base + 2 * BSS,
                                                            base, ws, 0);
        k_terms<<<dim3(S, 9, BB), dim3(256), 0, stream>>>(be, bb, cb, eb, ee, ce, sp, gb, ge,
                                                          edge, chart, ws, base);
    }
}